// Round 6
// baseline (7659.068 us; speedup 1.0000x reference)
//
#include <hip/hip_runtime.h>
#include <math.h>

#define Bsz 8
#define Tsz 4000
#define Csz 4
#define Dsz 256
#define H3  768
#define ROWT 8

// ---------- numerics matching jax fp32 semantics ----------
__device__ __forceinline__ float sigmoid_ref(float x){
  if (x >= 0.0f){ return 1.0f/(1.0f + expf(-x)); }
  float e = expf(x);
  return e/(1.0f+e);
}
__device__ __forceinline__ float bce_ref(float p, float y){
  float lp = fmaxf(logf(p), -100.0f);
  float lq = fmaxf(log1pf(-p), -100.0f);
  return -(y*lp + (1.0f-y)*lq);
}
__device__ __forceinline__ float wave_sum(float v){
  #pragma unroll
  for (int o=32;o>0;o>>=1) v += __shfl_xor(v, o, 64);
  return v;
}
__device__ __forceinline__ float block_sum(float v, float* red, int tid, int nw){
  v = wave_sum(v);
  if ((tid & 63) == 0) red[tid>>6] = v;
  __syncthreads();
  if (tid == 0){
    float t = 0.f;
    for (int i=0;i<nw;i++) t += red[i];
    red[0] = t;
  }
  __syncthreads();
  float r = red[0];
  __syncthreads();
  return r;
}
// IC-coherent 64-bit packed exchange (naturally-aligned 8B single-copy atomic)
__device__ __forceinline__ void st_pack(unsigned long long* p, unsigned long long v){
  __hip_atomic_store(p, v, __ATOMIC_RELAXED, __HIP_MEMORY_SCOPE_AGENT);
}
__device__ __forceinline__ unsigned long long ld_pack(const unsigned long long* p){
  return __hip_atomic_load(p, __ATOMIC_RELAXED, __HIP_MEMORY_SCOPE_AGENT);
}

// ---------- transpose 768x256 -> 256x768 (recompute-phase layout) ----------
__global__ __launch_bounds__(256) void k_transpose(const float* __restrict__ in,
                                                   float* __restrict__ out){
  int idx = blockIdx.x*256 + threadIdx.x;
  if (idx < H3*Dsz){
    int r = idx >> 8;
    int c = idx & 255;
    out[(size_t)c*H3 + r] = in[idx];
  }
}

// ---------- pack Wh[768][256] into the k_scan per-thread register layout ----------
// dst flat float id = ((cg*16+m)*1024 + hf*256 + g*64 + c_loc)*4 + e
// src = row(cg*256+hf*64+c_loc), col(g*64+m*4+e)
__global__ __launch_bounds__(256) void k_pack(const float* __restrict__ in,
                                              float* __restrict__ out){
  int id = blockIdx.x*256 + threadIdx.x;
  if (id < H3*Dsz){
    int e  = id & 3;
    int q  = id >> 2;
    int c_loc = q & 63;
    int g  = (q >> 6) & 3;
    int hf = (q >> 8) & 3;
    int m  = (q >> 10) & 15;
    int cg = q >> 14;
    int row = cg*256 + hf*64 + c_loc;
    int col = g*64 + m*4 + e;
    out[id] = in[(size_t)row*Dsz + col];
  }
}

// ---------- C[m,n] = sum_k A[m,k]*W[n,k] + bias[n] ----------
__global__ __launch_bounds__(256) void k_gemm64(const float* __restrict__ A,
    const float* __restrict__ W, const float* __restrict__ bias,
    float* __restrict__ C, int N){
  __shared__ float As[64][65];
  __shared__ float Ws[64][65];
  int tid = threadIdx.x;
  int tx = tid & 15, ty = tid >> 4;
  int m0 = blockIdx.x * 64;
  int n0 = blockIdx.y * 64;
  float acc[4][4];
  #pragma unroll
  for (int i=0;i<4;i++){
    #pragma unroll
    for (int j=0;j<4;j++) acc[i][j] = 0.f;
  }
  for (int k0=0;k0<Dsz;k0+=64){
    #pragma unroll
    for (int it=0; it<16; it++){
      int idx = tid + it*256;
      int r = idx >> 6, kk = idx & 63;
      As[r][kk] = A[(size_t)(m0+r)*Dsz + k0+kk];
      Ws[r][kk] = W[(size_t)(n0+r)*Dsz + k0+kk];
    }
    __syncthreads();
    #pragma unroll 8
    for (int kk=0;kk<64;kk++){
      float a0=As[ty*4+0][kk], a1=As[ty*4+1][kk], a2=As[ty*4+2][kk], a3=As[ty*4+3][kk];
      float b0=Ws[tx*4+0][kk], b1=Ws[tx*4+1][kk], b2=Ws[tx*4+2][kk], b3=Ws[tx*4+3][kk];
      acc[0][0]=fmaf(a0,b0,acc[0][0]); acc[0][1]=fmaf(a0,b1,acc[0][1]);
      acc[0][2]=fmaf(a0,b2,acc[0][2]); acc[0][3]=fmaf(a0,b3,acc[0][3]);
      acc[1][0]=fmaf(a1,b0,acc[1][0]); acc[1][1]=fmaf(a1,b1,acc[1][1]);
      acc[1][2]=fmaf(a1,b2,acc[1][2]); acc[1][3]=fmaf(a1,b3,acc[1][3]);
      acc[2][0]=fmaf(a2,b0,acc[2][0]); acc[2][1]=fmaf(a2,b1,acc[2][1]);
      acc[2][2]=fmaf(a2,b2,acc[2][2]); acc[2][3]=fmaf(a2,b3,acc[2][3]);
      acc[3][0]=fmaf(a3,b0,acc[3][0]); acc[3][1]=fmaf(a3,b1,acc[3][1]);
      acc[3][2]=fmaf(a3,b2,acc[3][2]); acc[3][3]=fmaf(a3,b3,acc[3][3]);
    }
    __syncthreads();
  }
  #pragma unroll
  for (int i=0;i<4;i++){
    #pragma unroll
    for (int j=0;j<4;j++){
      int n = n0 + tx*4 + j;
      C[(size_t)(m0+ty*4+i)*N + n] = acc[i][j] + bias[n];
    }
  }
}

// ---------- per-batch prep: order, vad loss, vf, cexcl/tact, N/posN/pos3, zero accum+hx ----------
__global__ __launch_bounds__(256) void k_prep(const int* __restrict__ label,
    const int* __restrict__ seqlen, const float* __restrict__ femb,
    const float* __restrict__ h0, float* __restrict__ falv, float* __restrict__ vf,
    int* __restrict__ tact, int* __restrict__ cexcl,
    int* __restrict__ nactg, int* __restrict__ orderg,
    float* __restrict__ accum, unsigned long long* __restrict__ hx){
  int b = blockIdx.x, tid = threadIdx.x;
  __shared__ int fa[4];
  __shared__ int ord[4];
  __shared__ float red[8];
  __shared__ int sc[256];
  __shared__ float h0s[256];
  if (tid < 4){
    accum[96 + b*4 + tid]  = 0.f;   // ltermg
    accum[128 + b*4 + tid] = 0.f;   // lfal3g
  }
  // zero packed exchange slots via IC-coherent atomics (stale-stamp safety)
  st_pack(&hx[(size_t)b*512 + tid],       0ull);
  st_pack(&hx[(size_t)b*512 + 256 + tid], 0ull);
  if (tid < 4) fa[tid] = 2147483647;
  h0s[tid] = h0[tid];
  __syncthreads();
  int L = seqlen[b];
  float lpos = 0.f, lspk = 0.f;
  for (int t=tid; t<Tsz; t+=256){
    const int* lr = label + ((size_t)b*Tsz + t)*4;
    int cnt2 = 0;
    #pragma unroll
    for (int c=0;c<4;c++){
      int v = lr[c];
      if (v > 0){ cnt2++; atomicMin(&fa[c], t); }
    }
    if (cnt2 > 0 && t < L) lpos += 1.f;
    lspk += (float)cnt2;
  }
  float pos    = block_sum(lpos, red, tid, 4);
  float spksum = block_sum(lspk, red, tid, 4);
  if (tid == 0) vf[b] = (float)L + spksum;
  if (tid == 0){
    int key[4]; bool used[4];
    for (int c=0;c<4;c++){ key[c] = (fa[c]==2147483647) ? (Tsz+1) : fa[c]; used[c]=false; }
    for (int k=0;k<4;k++){
      int best=-1, bk=2147483647;
      for (int c=0;c<4;c++) if (!used[c] && key[c] < bk){ bk = key[c]; best = c; }
      used[best] = true; ord[k] = best; orderg[b*4+k] = best;
    }
  }
  __syncthreads();
  float Tb = (float)L;
  const float eps = 1e-9f;
  float wp = Tb/(pos+eps), wn = Tb/(Tb-pos+eps);
  int wid = tid >> 6, lane = tid & 63;
  float lvad = 0.f;
  for (int t0=wid; t0<Tsz; t0+=4){
    if (t0 >= L) continue;
    const float* fr = femb + ((size_t)b*Tsz + t0)*Dsz;
    float s = fr[lane]*h0s[lane] + fr[lane+64]*h0s[lane+64]
            + fr[lane+128]*h0s[lane+128] + fr[lane+192]*h0s[lane+192];
    s = wave_sum(s);
    const int* lr = label + ((size_t)b*Tsz + t0)*4;
    int cnt2 = (lr[0]>0)+(lr[1]>0)+(lr[2]>0)+(lr[3]>0);
    float y = (cnt2>0) ? 1.f : 0.f;
    float w = (cnt2>0) ? wp : wn;
    if (lane == 0) lvad += w * bce_ref(sigmoid_ref(s), y);
  }
  float vadsum = block_sum(lvad, red, tid, 4);
  if (tid == 0) falv[b] = vadsum;
  __syncthreads();
  // per-speaker: cumsum of activity, tact list, and N/posN/pos3 counts
  for (int k=0;k<4;k++){
    int spk = ord[k];
    int off = 0;
    float myN = 0.f, myPos = 0.f, myP3 = 0.f;
    for (int c0=0;c0<4096;c0+=256){
      int t = c0 + tid;
      int a = (t < Tsz && label[((size_t)b*Tsz + t)*4 + spk] > 0) ? 1 : 0;
      sc[tid] = a;
      __syncthreads();
      for (int o=1;o<256;o<<=1){
        int v = (tid >= o) ? sc[tid-o] : 0;
        __syncthreads();
        sc[tid] += v;
        __syncthreads();
      }
      int incl = sc[tid];
      int tot  = sc[255];
      if (t < Tsz){
        int excl = incl - a;
        int ce = off + excl;
        cexcl[((size_t)(b*4+k))*Tsz + t] = ce;
        if (a) tact[((size_t)(b*4+k))*Tsz + ce] = t;
        if (ce >= 1 && t < L){ myN += 1.f; if (a) myPos += 1.f; }
        if (a){
          int l3 = 0;
          for (int k2=k+1;k2<4;k2++) l3 |= label[((size_t)b*Tsz + t)*4 + ord[k2]];
          if (l3) myP3 += 1.f;
        }
      }
      off += tot;
      __syncthreads();
    }
    if (tid == 0) nactg[b*4+k] = off;
    float Nv  = block_sum(myN,  red, tid, 4);
    float pNv = block_sum(myPos, red, tid, 4);
    float p3v = block_sum(myP3, red, tid, 4);
    if (tid == 0){
      accum[     b*4+k] = Nv;     // Ng
      accum[32 + b*4+k] = pNv;    // posNg
      accum[64 + b*4+k] = p3v;    // pos3g
    }
    __syncthreads();
  }
}

// ---------- scan kernel: 32 blocks = 8 batch x 4 slices; 192 weight VGPRs/thread ----------
__global__ __launch_bounds__(256, 1) void k_scan(int k,
    const float* __restrict__ xa, float* __restrict__ hids,
    const float* __restrict__ Wpka, const float* __restrict__ Wpkm,
    const float* __restrict__ bha_g, const float* __restrict__ bhm_g,
    const float* __restrict__ h0,
    const int* __restrict__ tact, const int* __restrict__ nactg,
    unsigned long long* __restrict__ hx,
    float* __restrict__ adderg, float* __restrict__ hpmg)
{
  const int b  = blockIdx.x & 7;
  const int hf = blockIdx.x >> 3;       // slice 0..3: owns dims [hf*64, hf*64+64)
  const int tid = threadIdx.x;
  const int wid = tid >> 6, lane = tid & 63;
  const int g = wid;                     // k-chunk 0..3 (64 k-dims)

  __shared__ __align__(16) float h_l[256];
  __shared__ float part[4*192];

  const float4* Wa4 = (const float4*)Wpka;
  const float4* Wm4 = (const float4*)Wpkm;

  // resident weights: 3 col-groups x 16 float4 = 192 VGPRs (coalesced load)
  float4 wreg0[16], wreg1[16], wreg2[16];
  #pragma unroll
  for (int m=0;m<16;m++){
    wreg0[m] = Wa4[(0*16+m)*1024 + hf*256 + tid];
    wreg1[m] = Wa4[(1*16+m)*1024 + hf*256 + tid];
    wreg2[m] = Wa4[(2*16+m)*1024 + hf*256 + tid];
  }

  int na = nactg[b*4+k];
  const int* tk = tact + (size_t)(b*4+k)*Tsz;

  h_l[tid] = h0[tid];
  float br=0.f, bz=0.f, bn=0.f;
  if (tid < 64){
    br = bha_g[hf*64+tid]; bz = bha_g[256+hf*64+tid]; bn = bha_g[512+hf*64+tid];
  }
  __syncthreads();

  unsigned long long* slot0 = hx + (size_t)b*512;
  const unsigned stamp_base = (unsigned)k*4096u;

  float xr=0.f, xz=0.f, xn=0.f, x2r=0.f, x2z=0.f, x2n=0.f;
  if (na > 0 && tid < 64){
    const float* xrow = xa + ((size_t)b*Tsz + tk[0])*H3;
    xr = xrow[hf*64+tid]; xz = xrow[256+hf*64+tid]; xn = xrow[512+hf*64+tid];
  }
  for (int j=0;j<na;j++){
    const unsigned stamp = stamp_base + (unsigned)j + 1u;
    if (tid < 64 && j+1 < na){
      const float* xrow = xa + ((size_t)b*Tsz + tk[j+1])*H3;
      x2r = xrow[hf*64+tid]; x2z = xrow[256+hf*64+tid]; x2n = xrow[512+hf*64+tid];
    }
    // FMA over this wave's 64-k chunk for 3 owned columns
    {
      const float4* h4 = (const float4*)h_l;
      float a0=0.f, a1=0.f, a2=0.f;
      #pragma unroll
      for (int m=0;m<16;m++){
        float4 hv = h4[g*16+m];
        a0 = fmaf(wreg0[m].w,hv.w, fmaf(wreg0[m].z,hv.z, fmaf(wreg0[m].y,hv.y, fmaf(wreg0[m].x,hv.x, a0))));
        a1 = fmaf(wreg1[m].w,hv.w, fmaf(wreg1[m].z,hv.z, fmaf(wreg1[m].y,hv.y, fmaf(wreg1[m].x,hv.x, a1))));
        a2 = fmaf(wreg2[m].w,hv.w, fmaf(wreg2[m].z,hv.z, fmaf(wreg2[m].y,hv.y, fmaf(wreg2[m].x,hv.x, a2))));
      }
      part[g*192 + lane]       = a0;
      part[g*192 + 64 + lane]  = a1;
      part[g*192 + 128 + lane] = a2;
    }
    __syncthreads();
    unsigned long long* slot = slot0 + (size_t)(stamp & 1u)*256;
    if (wid == 0){
      float h0p = part[tid]     + part[192+tid] + part[384+tid] + part[576+tid];
      float h1p = part[64+tid]  + part[256+tid] + part[448+tid] + part[640+tid];
      float h2p = part[128+tid] + part[320+tid] + part[512+tid] + part[704+tid];
      float r = sigmoid_ref(xr + br + h0p);
      float z = sigmoid_ref(xz + bz + h1p);
      float n = tanhf(xn + r*(bn + h2p));
      float hn = (1.f - z)*n + z*h_l[hf*64+tid];
      unsigned long long pv = ((unsigned long long)__float_as_uint(hn) << 32)
                            | (unsigned long long)stamp;
      st_pack(&slot[hf*64+tid], pv);
      hids[((size_t)b*Tsz + j)*Dsz + hf*64 + tid] = hn;
    } else if (wid <= 2){
      int i0 = (wid-1)*128 + lane;
      const unsigned long long* s0 = &slot[i0];
      const unsigned long long* s1 = &slot[i0+64];
      bool d0=false, d1=false;
      while (!(d0 && d1)){
        if (!d0){ unsigned long long v = ld_pack(s0);
          if ((unsigned)v == stamp){ h_l[i0] = __uint_as_float((unsigned)(v>>32)); d0=true; } }
        if (!d1){ unsigned long long v = ld_pack(s1);
          if ((unsigned)v == stamp){ h_l[i0+64] = __uint_as_float((unsigned)(v>>32)); d1=true; } }
      }
    }
    xr=x2r; xz=x2z; xn=x2n;
    __syncthreads();
  }

  // ---- hpm = adder @ Wh_m.T + bh_m (stream packed Whm, same layout) + adder store ----
  {
    const float4* h4 = (const float4*)h_l;
    float a0=0.f, a1=0.f, a2=0.f;
    #pragma unroll
    for (int m=0;m<16;m++){
      float4 hv = h4[g*16+m];
      float4 w0 = Wm4[(0*16+m)*1024 + hf*256 + tid];
      float4 w1 = Wm4[(1*16+m)*1024 + hf*256 + tid];
      float4 w2 = Wm4[(2*16+m)*1024 + hf*256 + tid];
      a0 = fmaf(w0.w,hv.w, fmaf(w0.z,hv.z, fmaf(w0.y,hv.y, fmaf(w0.x,hv.x, a0))));
      a1 = fmaf(w1.w,hv.w, fmaf(w1.z,hv.z, fmaf(w1.y,hv.y, fmaf(w1.x,hv.x, a1))));
      a2 = fmaf(w2.w,hv.w, fmaf(w2.z,hv.z, fmaf(w2.y,hv.y, fmaf(w2.x,hv.x, a2))));
    }
    part[g*192 + lane]       = a0;
    part[g*192 + 64 + lane]  = a1;
    part[g*192 + 128 + lane] = a2;
  }
  __syncthreads();
  if (wid == 0){
    float h0p = part[tid]     + part[192+tid] + part[384+tid] + part[576+tid];
    float h1p = part[64+tid]  + part[256+tid] + part[448+tid] + part[640+tid];
    float h2p = part[128+tid] + part[320+tid] + part[512+tid] + part[704+tid];
    hpmg[(size_t)b*H3 + hf*64 + tid]       = bhm_g[hf*64+tid] + h0p;
    hpmg[(size_t)b*H3 + 256 + hf*64 + tid] = bhm_g[256+hf*64+tid] + h1p;
    hpmg[(size_t)b*H3 + 512 + hf*64 + tid] = bhm_g[512+hf*64+tid] + h2p;
    adderg[(size_t)b*Dsz + hf*64 + tid] = h_l[hf*64+tid];
  }
}

// ---------- phase A: speaker score loss ----------
__global__ __launch_bounds__(256) void k_phaseA(int k,
    const int* __restrict__ label, const int* __restrict__ seqlen,
    const float* __restrict__ femb, const float* __restrict__ hids,
    const int* __restrict__ cexcl, const int* __restrict__ orderg,
    const float* __restrict__ accum, float* __restrict__ ltermg)
{
  const int b = blockIdx.x & 7, s = blockIdx.x >> 3;
  const int tid = threadIdx.x, wid = tid >> 6, lane = tid & 63;
  __shared__ float red[8];
  const float eps = 1e-9f;
  int spk = orderg[b*4+k];
  int L = seqlen[b];
  const int* ck = cexcl + (size_t)(b*4+k)*Tsz;
  float N    = accum[b*4+k];
  float posN = accum[32 + b*4+k];
  float w2p = N/(posN+eps), w2n = N/(N-posN+eps);
  float lterm = 0.f;
  const float4* femb4 = (const float4*)femb;
  const float4* hids4 = (const float4*)hids;
  for (int t0 = s*4 + wid; t0 < Tsz; t0 += 32){
    int ce = ck[t0];
    if (!(ce >= 1 && t0 < L)) continue;
    int jj = ce - 1;
    float4 f1 = femb4[((size_t)b*Tsz + t0)*64 + lane];
    float4 h1 = hids4[((size_t)b*Tsz + jj)*64 + lane];
    float sdot = f1.x*h1.x + f1.y*h1.y + f1.z*h1.z + f1.w*h1.w;
    sdot = wave_sum(sdot);
    float slab = (label[((size_t)b*Tsz + t0)*4 + spk] > 0) ? 1.f : 0.f;
    float w2 = (slab == 1.f) ? w2p : w2n;
    if (lane == 0) lterm += w2 * bce_ref(sigmoid_ref(sdot), slab);
  }
  float tsum = block_sum(lterm, red, tid, 4);
  if (tid == 0 && tsum != 0.f) atomicAdd(&ltermg[b*4+k], tsum);
}

// ---------- phase B: masking-GRU femb update + lab3 loss + xa/xm recompute ----------
__global__ __launch_bounds__(256) void k_phaseB(int k,
    const int* __restrict__ label,
    float* __restrict__ femb, float* __restrict__ xa, float* __restrict__ xm,
    const float* __restrict__ WiaT, const float* __restrict__ WimT,
    const float* __restrict__ bia_g, const float* __restrict__ bim_g,
    const float* __restrict__ h0,
    const int* __restrict__ tact, const int* __restrict__ nactg,
    const int* __restrict__ orderg,
    const float* __restrict__ hpmg, const float* __restrict__ adderg,
    const float* __restrict__ accum, float* __restrict__ lfal3g)
{
  const int b = blockIdx.x & 7, s = blockIdx.x >> 3;
  const int tid = threadIdx.x, wid = tid >> 6, lane = tid & 63;
  __shared__ __align__(16) float adder_l[256];
  __shared__ __align__(16) float h0s[256];
  __shared__ float hpm_l[768];
  __shared__ float red[8];
  __shared__ int ord2[4];
  __shared__ int rlist[600];
  __shared__ int rcnt_l;
  __shared__ __align__(16) float ev_et[ROWT][256];
  adder_l[tid] = adderg[(size_t)b*Dsz + tid];
  h0s[tid] = h0[tid];
  for (int i=tid;i<H3;i+=256) hpm_l[i] = hpmg[(size_t)b*H3 + i];
  if (tid < 4) ord2[tid] = orderg[b*4+tid];
  if (tid == 0) rcnt_l = 0;
  __syncthreads();
  int na = nactg[b*4+k];
  const int* tk = tact + (size_t)(b*4+k)*Tsz;
  const float eps = 1e-9f;
  float pos3 = accum[64 + b*4+k];
  float Lb = (float)na;
  float w3n = Lb/(Lb - pos3 + eps);
  float lfal = 0.f;
  for (int j0 = s + 8*wid; j0 < na; j0 += 32){
    int tj = tk[j0];
    const float* xmr = xm + ((size_t)b*Tsz + tj)*H3;
    float* fr = femb + ((size_t)b*Tsz + tj)*Dsz;
    float uq[4]; float dotp = 0.f;
    #pragma unroll
    for (int q=0;q<4;q++){
      int d = lane + q*64;
      float r = sigmoid_ref(xmr[d]       + hpm_l[d]);
      float z = sigmoid_ref(xmr[256+d]   + hpm_l[256+d]);
      float n = tanhf(xmr[512+d] + r*hpm_l[512+d]);
      float u = (1.f - z)*n + z*adder_l[d];
      uq[q] = u;
      dotp += u * h0s[d];
    }
    dotp = wave_sum(dotp);
    #pragma unroll
    for (int q=0;q<4;q++) fr[lane + q*64] = uq[q];
    int l3 = 0;
    for (int k2=k+1;k2<4;k2++) l3 |= label[((size_t)b*Tsz + tj)*4 + ord2[k2]];
    if (lane == 0){
      float y3 = (l3 > 0) ? 1.f : 0.f;
      float w3 = (y3 == 1.f) ? 1.f : w3n;
      lfal += w3 * bce_ref(sigmoid_ref(dotp), y3);
      if (l3){ int slot2 = atomicAdd(&rcnt_l, 1); rlist[slot2] = tj; }
    }
  }
  float fsum = block_sum(lfal, red, tid, 4);
  if (tid == 0 && fsum != 0.f) atomicAdd(&lfal3g[b*4+k], fsum);
  __syncthreads();

  if (k < 3){
    int nr = rcnt_l;
    for (int r0=0; r0<nr; r0+=ROWT){
      int nrows = nr - r0; if (nrows > ROWT) nrows = ROWT;
      for (int idx=tid; idx<nrows*256; idx+=256){
        int rr = idx >> 8, cc = idx & 255;
        ev_et[rr][cc] = femb[((size_t)b*Tsz + rlist[r0+rr])*Dsz + cc];
      }
      __syncthreads();
      {
        float accA[3][ROWT] = {};
        float accM[3][ROWT] = {};
        for (int j2=0;j2<256;j2+=4){
          float4 ef[ROWT];
          #pragma unroll
          for (int r=0;r<ROWT;r++) ef[r] = *(const float4*)&ev_et[r][j2];
          #pragma unroll
          for (int cc=0;cc<3;cc++){
            int col = tid + cc*256;
            float wa0 = WiaT[(size_t)j2*H3 + col],     wa1 = WiaT[(size_t)(j2+1)*H3 + col];
            float wa2 = WiaT[(size_t)(j2+2)*H3 + col], wa3 = WiaT[(size_t)(j2+3)*H3 + col];
            float wm0 = WimT[(size_t)j2*H3 + col],     wm1 = WimT[(size_t)(j2+1)*H3 + col];
            float wm2 = WimT[(size_t)(j2+2)*H3 + col], wm3 = WimT[(size_t)(j2+3)*H3 + col];
            #pragma unroll
            for (int r=0;r<ROWT;r++){
              accA[cc][r] = fmaf(ef[r].x, wa0, accA[cc][r]);
              accA[cc][r] = fmaf(ef[r].y, wa1, accA[cc][r]);
              accA[cc][r] = fmaf(ef[r].z, wa2, accA[cc][r]);
              accA[cc][r] = fmaf(ef[r].w, wa3, accA[cc][r]);
              accM[cc][r] = fmaf(ef[r].x, wm0, accM[cc][r]);
              accM[cc][r] = fmaf(ef[r].y, wm1, accM[cc][r]);
              accM[cc][r] = fmaf(ef[r].z, wm2, accM[cc][r]);
              accM[cc][r] = fmaf(ef[r].w, wm3, accM[cc][r]);
            }
          }
        }
        #pragma unroll
        for (int cc=0;cc<3;cc++){
          int col = tid + cc*256;
          #pragma unroll
          for (int r=0;r<ROWT;r++){
            if (r0 + r < nr){
              size_t rowoff = ((size_t)b*Tsz + rlist[r0+r])*H3;
              xa[rowoff + col] = bia_g[col] + accA[cc][r];
              xm[rowoff + col] = bim_g[col] + accM[cc][r];
            }
          }
        }
      }
      __syncthreads();
    }
  }
}

// ---------- final combine ----------
__global__ __launch_bounds__(64) void k_final(const float* __restrict__ accum,
    const float* __restrict__ falv, const float* __restrict__ vf,
    float* __restrict__ out){
  int b = threadIdx.x;
  if (b < 8){
    float sl = 0.f, fl = 0.f;
    for (int k=0;k<4;k++){
      float N = accum[b*4+k];
      if (N > 0.f) sl += accum[96 + b*4+k] / fmaxf(N, 1.f);
      fl += accum[128 + b*4+k];
    }
    out[b]     = sl * 0.25f;
    out[8 + b] = (falv[b] + fl) / (vf[b] + 1e-5f);
  }
}

extern "C" void kernel_launch(void* const* d_in, const int* in_sizes, int n_in,
                              void* d_out, int out_size, void* d_ws, size_t ws_size,
                              hipStream_t stream) {
  (void)in_sizes; (void)n_in; (void)out_size; (void)ws_size;
  const float* enc    = (const float*)d_in[0];
  const int*   seqlen = (const int*)d_in[1];
  const int*   label  = (const int*)d_in[2];
  const float* Wproj  = (const float*)d_in[3];
  const float* bproj  = (const float*)d_in[4];
  const float* Wia    = (const float*)d_in[5];
  const float* Wha    = (const float*)d_in[6];
  const float* bia    = (const float*)d_in[7];
  const float* bha    = (const float*)d_in[8];
  const float* Wim    = (const float*)d_in[9];
  const float* Whm    = (const float*)d_in[10];
  const float* bim    = (const float*)d_in[11];
  const float* bhm    = (const float*)d_in[12];
  const float* h0     = (const float*)d_in[13];
  float* out = (float*)d_out;

  float* p = (float*)d_ws;
  float* femb   = p; p += (size_t)Bsz*Tsz*Dsz;
  float* xa     = p; p += (size_t)Bsz*Tsz*H3;
  float* xm     = p; p += (size_t)Bsz*Tsz*H3;
  float* hids   = p; p += (size_t)Bsz*Tsz*Dsz;
  float* WiaT   = p; p += (size_t)H3*Dsz;
  float* WimT   = p; p += (size_t)H3*Dsz;
  float* Wpka   = p; p += (size_t)H3*Dsz;
  float* Wpkm   = p; p += (size_t)H3*Dsz;
  float* falv   = p; p += 8;
  float* vf     = p; p += 8;
  float* hpmg   = p; p += (size_t)Bsz*H3;
  float* adderg = p; p += (size_t)Bsz*Dsz;
  float* accum  = p; p += 160;             // Ng|posNg|pos3g|ltermg|lfal3g (5x32)
  unsigned long long* hx = (unsigned long long*)p; p += (size_t)Bsz*512*2;
  int* ip = (int*)p;
  int* tact  = ip; ip += (size_t)Bsz*Csz*Tsz;
  int* cexcl = ip; ip += (size_t)Bsz*Csz*Tsz;
  int* nact  = ip; ip += Bsz*Csz;
  int* order = ip; ip += Bsz*Csz;

  k_pack<<<768, 256, 0, stream>>>(Wha, Wpka);
  k_pack<<<768, 256, 0, stream>>>(Whm, Wpkm);
  k_transpose<<<768, 256, 0, stream>>>(Wia, WiaT);
  k_transpose<<<768, 256, 0, stream>>>(Wim, WimT);

  k_gemm64<<<dim3(500, 4), 256, 0, stream>>>(enc, Wproj, bproj, femb, Dsz);
  k_gemm64<<<dim3(500, 12), 256, 0, stream>>>(femb, Wia, bia, xa, H3);
  k_gemm64<<<dim3(500, 12), 256, 0, stream>>>(femb, Wim, bim, xm, H3);

  k_prep<<<Bsz, 256, 0, stream>>>(label, seqlen, femb, h0, falv, vf,
                                  tact, cexcl, nact, order, accum, hx);

  for (int k=0;k<4;k++){
    k_scan<<<32, 256, 0, stream>>>(k, xa, hids, Wpka, Wpkm, bha, bhm, h0,
                                   tact, nact, hx, adderg, hpmg);
    k_phaseA<<<64, 256, 0, stream>>>(k, label, seqlen, femb, hids, cexcl,
                                     order, accum, accum + 96);
    k_phaseB<<<64, 256, 0, stream>>>(k, label, femb, xa, xm, WiaT, WimT,
                                     bia, bim, h0, tact, nact, order,
                                     hpmg, adderg, accum, accum + 128);
  }
  k_final<<<1, 64, 0, stream>>>(accum, falv, vf, out);
}

// Round 8
// 6125.570 us; speedup vs baseline: 1.2503x; 1.2503x over previous
//
#include <hip/hip_runtime.h>
#include <math.h>

#define Bsz 8
#define Tsz 4000
#define Csz 4
#define Dsz 256
#define H3  768
#define ROWT 8

typedef __attribute__((ext_vector_type(8))) short bf8_t;   // 8 bf16 (4 VGPRs)
typedef __attribute__((ext_vector_type(4))) float f4_t;

// ---------- numerics matching jax fp32 semantics ----------
__device__ __forceinline__ float sigmoid_ref(float x){
  if (x >= 0.0f){ return 1.0f/(1.0f + expf(-x)); }
  float e = expf(x);
  return e/(1.0f+e);
}
__device__ __forceinline__ float bce_ref(float p, float y){
  float lp = fmaxf(logf(p), -100.0f);
  float lq = fmaxf(log1pf(-p), -100.0f);
  return -(y*lp + (1.0f-y)*lq);
}
__device__ __forceinline__ float wave_sum(float v){
  #pragma unroll
  for (int o=32;o>0;o>>=1) v += __shfl_xor(v, o, 64);
  return v;
}
__device__ __forceinline__ float block_sum(float v, float* red, int tid, int nw){
  v = wave_sum(v);
  if ((tid & 63) == 0) red[tid>>6] = v;
  __syncthreads();
  if (tid == 0){
    float t = 0.f;
    for (int i=0;i<nw;i++) t += red[i];
    red[0] = t;
  }
  __syncthreads();
  float r = red[0];
  __syncthreads();
  return r;
}
// agent-scope (IC-coherent) packed exchange — proven in R5/R6
__device__ __forceinline__ void st_pack(unsigned long long* p, unsigned long long v){
  __hip_atomic_store(p, v, __ATOMIC_RELAXED, __HIP_MEMORY_SCOPE_AGENT);
}
__device__ __forceinline__ unsigned long long ld_pack(const unsigned long long* p){
  return __hip_atomic_load(p, __ATOMIC_RELAXED, __HIP_MEMORY_SCOPE_AGENT);
}
// bf16 round-to-nearest-even helpers
__device__ __forceinline__ short f2bf(float x){
  unsigned u = __float_as_uint(x);
  unsigned r = (u + 0x7FFFu + ((u >> 16) & 1u)) >> 16;
  return (short)r;
}
__device__ __forceinline__ float bf2f(short b){
  return __uint_as_float(((unsigned)(unsigned short)b) << 16);
}

// ---------- transpose 768x256 -> 256x768 (phaseB recompute layout) ----------
__global__ __launch_bounds__(256) void k_transpose(const float* __restrict__ in,
                                                   float* __restrict__ out){
  int idx = blockIdx.x*256 + threadIdx.x;
  if (idx < H3*Dsz){
    int r = idx >> 8;
    int c = idx & 255;
    out[(size_t)c*H3 + r] = in[idx];
  }
}

// ---------- W fp32 -> bf16 hi/lo ----------
__global__ __launch_bounds__(256) void k_cvtW(const float* __restrict__ in,
    short* __restrict__ oh, short* __restrict__ ol){
  int i = blockIdx.x*256 + threadIdx.x;   // grid 768 -> 768*256
  float x = in[i];
  short h = f2bf(x);
  oh[i] = h;
  ol[i] = f2bf(x - bf2f(h));
}

// ---------- fp32 vector GEMM (femb only): C[m,n]=sum_k A[m,k]W[n,k]+b[n] ----------
__global__ __launch_bounds__(256) void k_gemm64(const float* __restrict__ A,
    const float* __restrict__ W, const float* __restrict__ bias,
    float* __restrict__ C, int N){
  __shared__ float As[64][65];
  __shared__ float Ws[64][65];
  int tid = threadIdx.x;
  int tx = tid & 15, ty = tid >> 4;
  int m0 = blockIdx.x * 64;
  int n0 = blockIdx.y * 64;
  float acc[4][4];
  #pragma unroll
  for (int i=0;i<4;i++){
    #pragma unroll
    for (int j=0;j<4;j++) acc[i][j] = 0.f;
  }
  for (int k0=0;k0<Dsz;k0+=64){
    #pragma unroll
    for (int it=0; it<16; it++){
      int idx = tid + it*256;
      int r = idx >> 6, kk = idx & 63;
      As[r][kk] = A[(size_t)(m0+r)*Dsz + k0+kk];
      Ws[r][kk] = W[(size_t)(n0+r)*Dsz + k0+kk];
    }
    __syncthreads();
    #pragma unroll 8
    for (int kk=0;kk<64;kk++){
      float a0=As[ty*4+0][kk], a1=As[ty*4+1][kk], a2=As[ty*4+2][kk], a3=As[ty*4+3][kk];
      float b0=Ws[tx*4+0][kk], b1=Ws[tx*4+1][kk], b2=Ws[tx*4+2][kk], b3=Ws[tx*4+3][kk];
      acc[0][0]=fmaf(a0,b0,acc[0][0]); acc[0][1]=fmaf(a0,b1,acc[0][1]);
      acc[0][2]=fmaf(a0,b2,acc[0][2]); acc[0][3]=fmaf(a0,b3,acc[0][3]);
      acc[1][0]=fmaf(a1,b0,acc[1][0]); acc[1][1]=fmaf(a1,b1,acc[1][1]);
      acc[1][2]=fmaf(a1,b2,acc[1][2]); acc[1][3]=fmaf(a1,b3,acc[1][3]);
      acc[2][0]=fmaf(a2,b0,acc[2][0]); acc[2][1]=fmaf(a2,b1,acc[2][1]);
      acc[2][2]=fmaf(a2,b2,acc[2][2]); acc[2][3]=fmaf(a2,b3,acc[2][3]);
      acc[3][0]=fmaf(a3,b0,acc[3][0]); acc[3][1]=fmaf(a3,b1,acc[3][1]);
      acc[3][2]=fmaf(a3,b2,acc[3][2]); acc[3][3]=fmaf(a3,b3,acc[3][3]);
    }
    __syncthreads();
  }
  #pragma unroll
  for (int i=0;i<4;i++){
    #pragma unroll
    for (int j=0;j<4;j++){
      int n = n0 + tx*4 + j;
      C[(size_t)(m0+ty*4+i)*N + n] = acc[i][j] + bias[n];
    }
  }
}

// ---------- split-bf16 MFMA GEMM: C[m,n]=sum_k A[m,k]W[n,k]+b[n], N=768 ----------
// A fp32 (converted hi/lo on the fly); W pre-split bf16 hi/lo.
// mfma_f32_16x16x32_bf16: A[m=lane&15][k=quad*8+j]; B[n=lane&15][k=quad*8+j];
// D col=lane&15 (n), row=quad*4+reg (m).  [guide §3, m89/m97-verified]
__global__ __launch_bounds__(256) void k_gemm_mfma(
    const float* __restrict__ A,
    const short* __restrict__ Wh, const short* __restrict__ Wl,
    const float* __restrict__ bias, float* __restrict__ C)
{
  int tid = threadIdx.x;
  int w = tid >> 6, lane = tid & 63;
  int l15 = lane & 15, quad = lane >> 4;
  int m0 = blockIdx.x*64 + w*16;
  int n0 = blockIdx.y*64;
  f4_t acc[4] = {{0.f,0.f,0.f,0.f},{0.f,0.f,0.f,0.f},{0.f,0.f,0.f,0.f},{0.f,0.f,0.f,0.f}};
  const float* arow = A + (size_t)(m0 + l15)*Dsz + quad*8;
  #pragma unroll 2
  for (int k0=0;k0<Dsz;k0+=32){
    float4 f0 = *(const float4*)(arow + k0);
    float4 f1 = *(const float4*)(arow + k0 + 4);
    float xs[8] = {f0.x,f0.y,f0.z,f0.w,f1.x,f1.y,f1.z,f1.w};
    bf8_t ah, al;
    #pragma unroll
    for (int e=0;e<8;e++){
      short h = f2bf(xs[e]);
      ah[e] = h;
      al[e] = f2bf(xs[e] - bf2f(h));
    }
    #pragma unroll
    for (int t=0;t<4;t++){
      size_t woff = (size_t)(n0 + t*16 + l15)*Dsz + k0 + quad*8;
      bf8_t bh = *(const bf8_t*)(Wh + woff);
      bf8_t bl = *(const bf8_t*)(Wl + woff);
      acc[t] = __builtin_amdgcn_mfma_f32_16x16x32_bf16(ah, bh, acc[t], 0,0,0);
      acc[t] = __builtin_amdgcn_mfma_f32_16x16x32_bf16(ah, bl, acc[t], 0,0,0);
      acc[t] = __builtin_amdgcn_mfma_f32_16x16x32_bf16(al, bh, acc[t], 0,0,0);
    }
  }
  #pragma unroll
  for (int t=0;t<4;t++){
    int n = n0 + t*16 + l15;
    float bv = bias[n];
    #pragma unroll
    for (int r=0;r<4;r++){
      int m = m0 + quad*4 + r;
      C[(size_t)m*H3 + n] = acc[t][r] + bv;
    }
  }
}

// ---------- prep0: order, vf, wp/wn; zero accum/falv/hx ----------
__global__ __launch_bounds__(256) void k_prep0(const int* __restrict__ label,
    const int* __restrict__ seqlen,
    float* __restrict__ falv, float* __restrict__ vf,
    int* __restrict__ orderg, float* __restrict__ accum,
    unsigned long long* __restrict__ hx){
  int b = blockIdx.x, tid = threadIdx.x;
  __shared__ int fa[4];
  __shared__ float red[8];
  if (tid < 4){
    fa[tid] = 2147483647;
    accum[96 + b*4 + tid]  = 0.f;   // lterm
    accum[128 + b*4 + tid] = 0.f;   // lfal3
  }
  if (tid == 0) falv[b] = 0.f;
  st_pack(&hx[(size_t)b*512 + tid],       0ull);
  st_pack(&hx[(size_t)b*512 + 256 + tid], 0ull);
  __syncthreads();
  int L = seqlen[b];
  float lpos = 0.f, lspk = 0.f;
  for (int t=tid; t<Tsz; t+=256){
    const int* lr = label + ((size_t)b*Tsz + t)*4;
    int cnt2 = 0;
    #pragma unroll
    for (int c=0;c<4;c++){
      int v = lr[c];
      if (v > 0){ cnt2++; atomicMin(&fa[c], t); }
    }
    if (cnt2 > 0 && t < L) lpos += 1.f;
    lspk += (float)cnt2;
  }
  float pos    = block_sum(lpos, red, tid, 4);
  float spksum = block_sum(lspk, red, tid, 4);
  if (tid == 0){
    vf[b] = (float)L + spksum;
    const float eps = 1e-9f;
    float Tb = (float)L;
    accum[160 + b] = Tb/(pos+eps);       // wp
    accum[168 + b] = Tb/(Tb-pos+eps);    // wn
    int key[4]; bool used[4];
    for (int c=0;c<4;c++){ key[c] = (fa[c]==2147483647) ? (Tsz+1) : fa[c]; used[c]=false; }
    for (int k=0;k<4;k++){
      int best=-1, bk=2147483647;
      for (int c=0;c<4;c++) if (!used[c] && key[c] < bk){ bk = key[c]; best = c; }
      used[best] = true; orderg[b*4+k] = best;
    }
  }
}

// ---------- prep1: one block per (b,k): shfl-scan cumsum, tact/cexcl, counts ----------
__global__ __launch_bounds__(256) void k_prep1(const int* __restrict__ label,
    const int* __restrict__ seqlen,
    int* __restrict__ tact, int* __restrict__ cexcl, int* __restrict__ nactg,
    const int* __restrict__ orderg, float* __restrict__ accum){
  int b = blockIdx.x & 7, k = blockIdx.x >> 3;
  int tid = threadIdx.x, wv = tid >> 6, lane = tid & 63;
  __shared__ int ord[4];
  __shared__ int swl[4];
  __shared__ float red[8];
  if (tid < 4) ord[tid] = orderg[b*4+tid];
  __syncthreads();
  int L = seqlen[b];
  int spk = ord[k];
  int off = 0;
  float myN = 0.f, myPos = 0.f, myP3 = 0.f;
  for (int c0=0;c0<4096;c0+=256){
    int t = c0 + tid;
    int a = (t < Tsz && label[((size_t)b*Tsz + t)*4 + spk] > 0) ? 1 : 0;
    int v = a;
    #pragma unroll
    for (int o=1;o<64;o<<=1){
      int u = __shfl_up(v, o, 64);
      if (lane >= o) v += u;
    }
    if (lane == 63) swl[wv] = v;
    __syncthreads();
    int wpre = 0, tot = 0;
    #pragma unroll
    for (int w2=0; w2<4; w2++){
      int sv = swl[w2];
      if (w2 < wv) wpre += sv;
      tot += sv;
    }
    int incl = v + wpre;
    if (t < Tsz){
      int ce = off + incl - a;
      cexcl[((size_t)(b*4+k))*Tsz + t] = ce;
      if (a) tact[((size_t)(b*4+k))*Tsz + ce] = t;
      if (ce >= 1 && t < L){ myN += 1.f; if (a) myPos += 1.f; }
      if (a){
        int l3 = 0;
        for (int k2=k+1;k2<4;k2++) l3 |= label[((size_t)b*Tsz + t)*4 + ord[k2]];
        if (l3) myP3 += 1.f;
      }
    }
    off += tot;
    __syncthreads();
  }
  if (tid == 0) nactg[b*4+k] = off;
  float Nv  = block_sum(myN,  red, tid, 4);
  float pNv = block_sum(myPos, red, tid, 4);
  float p3v = block_sum(myP3, red, tid, 4);
  if (tid == 0){
    accum[     b*4+k] = Nv;
    accum[32 + b*4+k] = pNv;
    accum[64 + b*4+k] = p3v;
  }
}

// ---------- vad loss: 64 blocks ----------
__global__ __launch_bounds__(256) void k_vad(const int* __restrict__ label,
    const int* __restrict__ seqlen, const float* __restrict__ femb,
    const float* __restrict__ h0, const float* __restrict__ accum,
    float* __restrict__ falv){
  int b = blockIdx.x & 7, s = blockIdx.x >> 3;
  int tid = threadIdx.x, wid = tid >> 6, lane = tid & 63;
  __shared__ __align__(16) float h0s[256];
  __shared__ float red[8];
  h0s[tid] = h0[tid];
  __syncthreads();
  int L = seqlen[b];
  float wp = accum[160 + b], wn = accum[168 + b];
  float lvad = 0.f;
  const float4* femb4 = (const float4*)femb;
  const float4* h04 = (const float4*)h0s;
  for (int t0 = s*4 + wid; t0 < L; t0 += 32){
    float4 f1 = femb4[((size_t)b*Tsz + t0)*64 + lane];
    float4 hv = h04[lane];
    float sdot = f1.x*hv.x + f1.y*hv.y + f1.z*hv.z + f1.w*hv.w;
    sdot = wave_sum(sdot);
    const int* lr = label + ((size_t)b*Tsz + t0)*4;
    int cnt2 = (lr[0]>0)+(lr[1]>0)+(lr[2]>0)+(lr[3]>0);
    float y = (cnt2>0) ? 1.f : 0.f;
    float w = (cnt2>0) ? wp : wn;
    if (lane == 0) lvad += w * bce_ref(sigmoid_ref(sdot), y);
  }
  float vsum = block_sum(lvad, red, tid, 4);
  if (tid == 0 && vsum != 0.f) atomicAdd(&falv[b], vsum);
}

// ---------- scan: 64 blocks = 8 batch x 8 slices; 96 weight VGPRs (R5-proven) ----------
__global__ __launch_bounds__(256, 1) void k_scan(int k,
    const float* __restrict__ xa, float* __restrict__ hids,
    const float* __restrict__ Wha, const float* __restrict__ Whm,
    const float* __restrict__ bha_g, const float* __restrict__ bhm_g,
    const float* __restrict__ h0,
    const int* __restrict__ tact, const int* __restrict__ nactg,
    unsigned long long* __restrict__ hx,
    float* __restrict__ adderg, float* __restrict__ hpmg)
{
  const int b = blockIdx.x & 7;
  const int s = blockIdx.x >> 3;   // slice 0..7, owns dims [s*32, s*32+32)
  const int tid = threadIdx.x;
  const int wid = tid >> 6, lane = tid & 63;
  const int dd = tid & 31, ii = tid >> 5;
  const int dglob = s*32 + dd;

  __shared__ __align__(16) float h_l[256];
  __shared__ float part[768];

  // resident weights: 96 VGPRs/thread (R5-verified at VGPR_Count ~160)
  float4 wr0[8], wr1[8], wr2[8];
  #pragma unroll
  for (int m=0;m<8;m++){
    wr0[m] = *(const float4*)&Wha[((size_t)(      dglob))*Dsz + ii*32 + m*4];
    wr1[m] = *(const float4*)&Wha[((size_t)(256 + dglob))*Dsz + ii*32 + m*4];
    wr2[m] = *(const float4*)&Wha[((size_t)(512 + dglob))*Dsz + ii*32 + m*4];
  }
  float br=0.f, bz=0.f, bn=0.f;
  if (tid < 32){ br = bha_g[dglob]; bz = bha_g[256+dglob]; bn = bha_g[512+dglob]; }
  h_l[tid] = h0[tid];
  __syncthreads();

  int na = nactg[b*4+k];
  const int* tk = tact + (size_t)(b*4+k)*Tsz;
  unsigned long long* hxb = hx + (size_t)b*512;
  unsigned stamp = (unsigned)k*4096u + 1u;

  float xr=0.f, xz=0.f, xn=0.f, x2r=0.f, x2z=0.f, x2n=0.f;
  if (na > 0 && tid < 32){
    const float* xrow = xa + ((size_t)b*Tsz + tk[0])*H3;
    xr = xrow[dglob]; xz = xrow[256+dglob]; xn = xrow[512+dglob];
  }
  for (int j=0;j<na;j++, stamp++){
    if (tid < 32 && j+1 < na){
      const float* xrow = xa + ((size_t)b*Tsz + tk[j+1])*H3;
      x2r = xrow[dglob]; x2z = xrow[256+dglob]; x2n = xrow[512+dglob];
    }
    {
      const float4* h4 = (const float4*)h_l;
      float a0=0.f, a1=0.f, a2=0.f;
      #pragma unroll
      for (int m=0;m<8;m++){
        float4 hv = h4[ii*8+m];
        a0 = fmaf(wr0[m].w,hv.w, fmaf(wr0[m].z,hv.z, fmaf(wr0[m].y,hv.y, fmaf(wr0[m].x,hv.x, a0))));
        a1 = fmaf(wr1[m].w,hv.w, fmaf(wr1[m].z,hv.z, fmaf(wr1[m].y,hv.y, fmaf(wr1[m].x,hv.x, a1))));
        a2 = fmaf(wr2[m].w,hv.w, fmaf(wr2[m].z,hv.z, fmaf(wr2[m].y,hv.y, fmaf(wr2[m].x,hv.x, a2))));
      }
      part[      ii*32 + dd] = a0;
      part[256 + ii*32 + dd] = a1;
      part[512 + ii*32 + dd] = a2;
    }
    __syncthreads();
    unsigned long long* slot = hxb + (size_t)(stamp & 1u)*256;
    if (tid < 32){
      float h0p=0.f, h1p=0.f, h2p=0.f;
      #pragma unroll
      for (int i2=0;i2<8;i2++){
        h0p += part[      i2*32 + tid];
        h1p += part[256 + i2*32 + tid];
        h2p += part[512 + i2*32 + tid];
      }
      float r = sigmoid_ref(xr + br + h0p);
      float z = sigmoid_ref(xz + bz + h1p);
      float n = tanhf(xn + r*(bn + h2p));
      float hn = (1.f - z)*n + z*h_l[dglob];
      unsigned long long pv = ((unsigned long long)__float_as_uint(hn) << 32)
                            | (unsigned long long)stamp;
      st_pack(&slot[dglob], pv);                    // one publish: data+flag
      hids[((size_t)b*Tsz + j)*Dsz + dglob] = hn;   // plain store, off critical path
    } else if (wid == 1 || wid == 2){
      int i0 = (wid-1)*128 + lane;
      const unsigned long long* s0 = &slot[i0];
      const unsigned long long* s1 = &slot[i0+64];
      unsigned long long e0, e1;
      for(;;){
        e0 = ld_pack(s0);    // both loads issue back-to-back; single drain
        e1 = ld_pack(s1);
        if ((unsigned)e0 == stamp && (unsigned)e1 == stamp) break;
      }
      h_l[i0]    = __uint_as_float((unsigned)(e0 >> 32));
      h_l[i0+64] = __uint_as_float((unsigned)(e1 >> 32));
    }
    xr = x2r; xz = x2z; xn = x2n;
    __syncthreads();
  }

  // ---- hpm for this slice's 96 cols + adder store ----
  {
    const float4* a4 = (const float4*)h_l;
    for (int cc=0; cc<24; cc++){
      int c2 = wid*24 + cc;
      int row = (c2 >> 5)*256 + s*32 + (c2 & 31);
      const float4* wrow = (const float4*)&Whm[(size_t)row*Dsz];
      float4 wv = wrow[lane];
      float4 av = a4[lane];
      float sdot = wv.x*av.x + wv.y*av.y + wv.z*av.z + wv.w*av.w;
      sdot = wave_sum(sdot);
      if (lane == 0) hpmg[(size_t)b*H3 + row] = bhm_g[row] + sdot;
    }
  }
  if (s == 0) adderg[(size_t)b*Dsz + tid] = h_l[tid];
}

// ---------- phase A: speaker score loss ----------
__global__ __launch_bounds__(256) void k_phaseA(int k,
    const int* __restrict__ label, const int* __restrict__ seqlen,
    const float* __restrict__ femb, const float* __restrict__ hids,
    const int* __restrict__ cexcl, const int* __restrict__ orderg,
    const float* __restrict__ accum, float* __restrict__ ltermg)
{
  const int b = blockIdx.x & 7, s = blockIdx.x >> 3;
  const int tid = threadIdx.x, wid = tid >> 6, lane = tid & 63;
  __shared__ float red[8];
  const float eps = 1e-9f;
  int spk = orderg[b*4+k];
  int L = seqlen[b];
  const int* ck = cexcl + (size_t)(b*4+k)*Tsz;
  float N    = accum[b*4+k];
  float posN = accum[32 + b*4+k];
  float w2p = N/(posN+eps), w2n = N/(N-posN+eps);
  float lterm = 0.f;
  const float4* femb4 = (const float4*)femb;
  const float4* hids4 = (const float4*)hids;
  for (int t0 = s*4 + wid; t0 < Tsz; t0 += 32){
    int ce = ck[t0];
    if (!(ce >= 1 && t0 < L)) continue;
    int jj = ce - 1;
    float4 f1 = femb4[((size_t)b*Tsz + t0)*64 + lane];
    float4 h1 = hids4[((size_t)b*Tsz + jj)*64 + lane];
    float sdot = f1.x*h1.x + f1.y*h1.y + f1.z*h1.z + f1.w*h1.w;
    sdot = wave_sum(sdot);
    float slab = (label[((size_t)b*Tsz + t0)*4 + spk] > 0) ? 1.f : 0.f;
    float w2 = (slab == 1.f) ? w2p : w2n;
    if (lane == 0) lterm += w2 * bce_ref(sigmoid_ref(sdot), slab);
  }
  float tsum = block_sum(lterm, red, tid, 4);
  if (tid == 0 && tsum != 0.f) atomicAdd(&ltermg[b*4+k], tsum);
}

// ---------- phase B: masking-GRU femb update + lab3 loss + xa/xm recompute ----------
__global__ __launch_bounds__(256) void k_phaseB(int k,
    const int* __restrict__ label,
    float* __restrict__ femb, float* __restrict__ xa, float* __restrict__ xm,
    const float* __restrict__ WiaT, const float* __restrict__ WimT,
    const float* __restrict__ bia_g, const float* __restrict__ bim_g,
    const float* __restrict__ h0,
    const int* __restrict__ tact, const int* __restrict__ nactg,
    const int* __restrict__ orderg,
    const float* __restrict__ hpmg, const float* __restrict__ adderg,
    const float* __restrict__ accum, float* __restrict__ lfal3g)
{
  const int b = blockIdx.x & 7, s = blockIdx.x >> 3;
  const int tid = threadIdx.x, wid = tid >> 6, lane = tid & 63;
  __shared__ __align__(16) float adder_l[256];
  __shared__ __align__(16) float h0s[256];
  __shared__ float hpm_l[768];
  __shared__ float red[8];
  __shared__ int ord2[4];
  __shared__ int rlist[600];
  __shared__ int rcnt_l;
  __shared__ __align__(16) float ev_et[ROWT][256];
  adder_l[tid] = adderg[(size_t)b*Dsz + tid];
  h0s[tid] = h0[tid];
  for (int i=tid;i<H3;i+=256) hpm_l[i] = hpmg[(size_t)b*H3 + i];
  if (tid < 4) ord2[tid] = orderg[b*4+tid];
  if (tid == 0) rcnt_l = 0;
  __syncthreads();
  int na = nactg[b*4+k];
  const int* tk = tact + (size_t)(b*4+k)*Tsz;
  const float eps = 1e-9f;
  float pos3 = accum[64 + b*4+k];
  float Lb = (float)na;
  float w3n = Lb/(Lb - pos3 + eps);
  float lfal = 0.f;
  for (int j0 = s + 8*wid; j0 < na; j0 += 32){
    int tj = tk[j0];
    const float* xmr = xm + ((size_t)b*Tsz + tj)*H3;
    float* fr = femb + ((size_t)b*Tsz + tj)*Dsz;
    float uq[4]; float dotp = 0.f;
    #pragma unroll
    for (int q=0;q<4;q++){
      int d = lane + q*64;
      float r = sigmoid_ref(xmr[d]       + hpm_l[d]);
      float z = sigmoid_ref(xmr[256+d]   + hpm_l[256+d]);
      float n = tanhf(xmr[512+d] + r*hpm_l[512+d]);
      float u = (1.f - z)*n + z*adder_l[d];
      uq[q] = u;
      dotp += u * h0s[d];
    }
    dotp = wave_sum(dotp);
    #pragma unroll
    for (int q=0;q<4;q++) fr[lane + q*64] = uq[q];
    int l3 = 0;
    for (int k2=k+1;k2<4;k2++) l3 |= label[((size_t)b*Tsz + tj)*4 + ord2[k2]];
    if (lane == 0){
      float y3 = (l3 > 0) ? 1.f : 0.f;
      float w3 = (y3 == 1.f) ? 1.f : w3n;
      lfal += w3 * bce_ref(sigmoid_ref(dotp), y3);
      if (l3){ int slot2 = atomicAdd(&rcnt_l, 1); rlist[slot2] = tj; }
    }
  }
  float fsum = block_sum(lfal, red, tid, 4);
  if (tid == 0 && fsum != 0.f) atomicAdd(&lfal3g[b*4+k], fsum);
  __syncthreads();

  if (k < 3){
    int nr = rcnt_l;
    for (int r0=0; r0<nr; r0+=ROWT){
      int nrows = nr - r0; if (nrows > ROWT) nrows = ROWT;
      for (int idx=tid; idx<nrows*256; idx+=256){
        int rr = idx >> 8, cc = idx & 255;
        ev_et[rr][cc] = femb[((size_t)b*Tsz + rlist[r0+rr])*Dsz + cc];
      }
      __syncthreads();
      {
        float accA[3][ROWT] = {};
        float accM[3][ROWT] = {};
        for (int j2=0;j2<256;j2+=4){
          float4 ef[ROWT];
          #pragma unroll
          for (int r=0;r<ROWT;r++) ef[r] = *(const float4*)&ev_et[r][j2];
          #pragma unroll
          for (int cc=0;cc<3;cc++){
            int col = tid + cc*256;
            float wa0 = WiaT[(size_t)j2*H3 + col],     wa1 = WiaT[(size_t)(j2+1)*H3 + col];
            float wa2 = WiaT[(size_t)(j2+2)*H3 + col], wa3 = WiaT[(size_t)(j2+3)*H3 + col];
            float wm0 = WimT[(size_t)j2*H3 + col],     wm1 = WimT[(size_t)(j2+1)*H3 + col];
            float wm2 = WimT[(size_t)(j2+2)*H3 + col], wm3 = WimT[(size_t)(j2+3)*H3 + col];
            #pragma unroll
            for (int r=0;r<ROWT;r++){
              accA[cc][r] = fmaf(ef[r].x, wa0, accA[cc][r]);
              accA[cc][r] = fmaf(ef[r].y, wa1, accA[cc][r]);
              accA[cc][r] = fmaf(ef[r].z, wa2, accA[cc][r]);
              accA[cc][r] = fmaf(ef[r].w, wa3, accA[cc][r]);
              accM[cc][r] = fmaf(ef[r].x, wm0, accM[cc][r]);
              accM[cc][r] = fmaf(ef[r].y, wm1, accM[cc][r]);
              accM[cc][r] = fmaf(ef[r].z, wm2, accM[cc][r]);
              accM[cc][r] = fmaf(ef[r].w, wm3, accM[cc][r]);
            }
          }
        }
        #pragma unroll
        for (int cc=0;cc<3;cc++){
          int col = tid + cc*256;
          #pragma unroll
          for (int r=0;r<ROWT;r++){
            if (r0 + r < nr){
              size_t rowoff = ((size_t)b*Tsz + rlist[r0+r])*H3;
              xa[rowoff + col] = bia_g[col] + accA[cc][r];
              xm[rowoff + col] = bim_g[col] + accM[cc][r];
            }
          }
        }
      }
      __syncthreads();
    }
  }
}

// ---------- final combine ----------
__global__ __launch_bounds__(64) void k_final(const float* __restrict__ accum,
    const float* __restrict__ falv, const float* __restrict__ vf,
    float* __restrict__ out){
  int b = threadIdx.x;
  if (b < 8){
    float sl = 0.f, fl = 0.f;
    for (int k=0;k<4;k++){
      float N = accum[b*4+k];
      if (N > 0.f) sl += accum[96 + b*4+k] / fmaxf(N, 1.f);
      fl += accum[128 + b*4+k];
    }
    out[b]     = sl * 0.25f;
    out[8 + b] = (falv[b] + fl) / (vf[b] + 1e-5f);
  }
}

extern "C" void kernel_launch(void* const* d_in, const int* in_sizes, int n_in,
                              void* d_out, int out_size, void* d_ws, size_t ws_size,
                              hipStream_t stream) {
  (void)in_sizes; (void)n_in; (void)out_size; (void)ws_size;
  const float* enc    = (const float*)d_in[0];
  const int*   seqlen = (const int*)d_in[1];
  const int*   label  = (const int*)d_in[2];
  const float* Wproj  = (const float*)d_in[3];
  const float* bproj  = (const float*)d_in[4];
  const float* Wia    = (const float*)d_in[5];
  const float* Wha    = (const float*)d_in[6];
  const float* bia    = (const float*)d_in[7];
  const float* bha    = (const float*)d_in[8];
  const float* Wim    = (const float*)d_in[9];
  const float* Whm    = (const float*)d_in[10];
  const float* bim    = (const float*)d_in[11];
  const float* bhm    = (const float*)d_in[12];
  const float* h0     = (const float*)d_in[13];
  float* out = (float*)d_out;

  float* p = (float*)d_ws;
  float* femb   = p; p += (size_t)Bsz*Tsz*Dsz;
  float* xa     = p; p += (size_t)Bsz*Tsz*H3;
  float* xm     = p; p += (size_t)Bsz*Tsz*H3;
  float* hids   = p; p += (size_t)Bsz*Tsz*Dsz;
  float* WiaT   = p; p += (size_t)H3*Dsz;
  float* WimT   = p; p += (size_t)H3*Dsz;
  float* falv   = p; p += 8;
  float* vf     = p; p += 8;
  float* hpmg   = p; p += (size_t)Bsz*H3;
  float* adderg = p; p += (size_t)Bsz*Dsz;
  float* accum  = p; p += 192;             // Ng|posN|pos3|lterm|lfal3|wp|wn
  unsigned long long* hx = (unsigned long long*)p; p += (size_t)Bsz*512*2;
  short* Wiah = (short*)p;                 // 4 x H3*Dsz shorts = 2 x H3*Dsz floats
  short* Wial = Wiah + (size_t)H3*Dsz;
  short* Wimh = Wial + (size_t)H3*Dsz;
  short* Wiml = Wimh + (size_t)H3*Dsz;
  p += 2*(size_t)H3*Dsz;
  int* ip = (int*)p;
  int* tact  = ip; ip += (size_t)Bsz*Csz*Tsz;
  int* cexcl = ip; ip += (size_t)Bsz*Csz*Tsz;
  int* nact  = ip; ip += Bsz*Csz;
  int* order = ip; ip += Bsz*Csz;

  k_prep0<<<Bsz, 256, 0, stream>>>(label, seqlen, falv, vf, order, accum, hx);
  k_cvtW<<<768, 256, 0, stream>>>(Wia, Wiah, Wial);
  k_cvtW<<<768, 256, 0, stream>>>(Wim, Wimh, Wiml);
  k_transpose<<<768, 256, 0, stream>>>(Wia, WiaT);
  k_transpose<<<768, 256, 0, stream>>>(Wim, WimT);

  k_gemm64<<<dim3(500, 4), 256, 0, stream>>>(enc, Wproj, bproj, femb, Dsz);
  k_gemm_mfma<<<dim3(500, 12), 256, 0, stream>>>(femb, Wiah, Wial, bia, xa);
  k_gemm_mfma<<<dim3(500, 12), 256, 0, stream>>>(femb, Wimh, Wiml, bim, xm);

  k_prep1<<<32, 256, 0, stream>>>(label, seqlen, tact, cexcl, nact, order, accum);
  k_vad<<<64, 256, 0, stream>>>(label, seqlen, femb, h0, accum, falv);

  for (int k=0;k<4;k++){
    k_scan<<<64, 256, 0, stream>>>(k, xa, hids, Wha, Whm, bha, bhm, h0,
                                   tact, nact, hx, adderg, hpmg);
    k_phaseA<<<64, 256, 0, stream>>>(k, label, seqlen, femb, hids, cexcl,
                                     order, accum, accum + 96);
    k_phaseB<<<64, 256, 0, stream>>>(k, label, femb, xa, xm, WiaT, WimT,
                                     bia, bim, h0, tact, nact, order,
                                     hpmg, adderg, accum, accum + 128);
  }
  k_final<<<1, 64, 0, stream>>>(accum, falv, vf, out);
}